// Round 2
// baseline (705.379 us; speedup 1.0000x reference)
//
#include <hip/hip_runtime.h>

typedef unsigned short u16;
typedef short short8 __attribute__((ext_vector_type(8)));   // 8 bf16 as i16 (MFMA operand)
typedef float f32x4 __attribute__((ext_vector_type(4)));

#define NEG_MASK -4294967295.0f   // -2^32+1 in f32

__device__ __forceinline__ u16 f2bf(float f) {
    unsigned int x = __float_as_uint(f);
    unsigned int r = (x + 0x7FFFu + ((x >> 16) & 1u)) >> 16;   // RNE
    return (u16)r;
}
__device__ __forceinline__ short8 cvt8(float4 a, float4 b) {
    union { short8 v; u16 u[8]; } r;
    r.u[0] = f2bf(a.x); r.u[1] = f2bf(a.y); r.u[2] = f2bf(a.z); r.u[3] = f2bf(a.w);
    r.u[4] = f2bf(b.x); r.u[5] = f2bf(b.y); r.u[6] = f2bf(b.z); r.u[7] = f2bf(b.w);
    return r.v;
}

// B=4096, T=200 (13 tiles of 16), D=64, H1=80, H2=40(pad 48, K2 pad 96), C=64
// Round 2: occupancy push. H1p LDS staging buffer (13.3 KB) eliminated via
// swapped-operand MFMA: GEMM1 computes H1^T (t lane-local), a 20-shfl in-register
// regrouping builds GEMM2's B-fragments, GEMM2 computes H2^T, logits reduce is
// 2 shfl_xor. LDS 39.4 KB -> ~25.7 KB => 6 blocks/CU (was 4). VGPR capped for
// 6 waves/SIMD via __launch_bounds__(256,6).
__global__ __launch_bounds__(256, 6) void din_kernel(
    const float* __restrict__ qp, const float* __restrict__ kp,
    const int* __restrict__ maskp, const int* __restrict__ catep,
    const float* __restrict__ W1p, const float* __restrict__ b1p,
    const float* __restrict__ a1p, const float* __restrict__ W2p,
    const float* __restrict__ b2p, const float* __restrict__ a2p,
    const float* __restrict__ wfp, const float* __restrict__ bfp,
    float* __restrict__ outp)
{
    // Mt (B-op GEMM1, [h][d], stride 72) | W2t (A-op GEMM2, [g][h], stride 104, zero-padded)
    // Reused after the GEMM phase as cate_acc[64][64] f32 (16384 B <= 21504 B)
    __shared__ __align__(16) u16 MtW2t[80*72 + 48*104];      // 21504 B
    __shared__ __align__(16) float logits_s[200];            // phase0: qW partials alias
    __shared__ __align__(16) float q_s[64], qW_s[80], a1_s[80];
    __shared__ __align__(16) float a2_s[48], b2_s[48], wf_s[48];
    __shared__ float s_c[64], red_s[8], bf_s;
    __shared__ int cate_s[200];
    __shared__ int mask_s[200];

    u16* Mt  = MtW2t;
    u16* W2t = MtW2t + 80*72;
    float* cate_acc = (float*)MtW2t;
    float* qW2 = logits_s;   // alias: dead before logits are first written (phase 1)

    const int tid  = threadIdx.x;
    const int b    = blockIdx.x;
    const int wid  = tid >> 6;
    const int lane = tid & 63;
    const int i16  = lane & 15;
    const int q4   = lane >> 4;
    const float* kb = kp + (size_t)b * 12800;   // k[b] : [200][64] f32

    // ---------- Phase 0a: zeros + scalar staging ----------
    {
        unsigned int* w2z = (unsigned int*)W2t;
        for (int i = tid; i < (48*104)/2; i += 256) w2z[i] = 0u;  // W2t pad rows/cols
    }
    if (tid < 64) { s_c[tid] = 0.f; q_s[tid] = qp[(size_t)b*64 + tid]; }
    if (tid < 48) {
        wf_s[tid] = (tid < 40) ? wfp[tid] : 0.f;
        a2_s[tid] = (tid < 40) ? a2p[tid] : 0.f;
        b2_s[tid] = (tid < 40) ? b2p[tid] : 0.f;
    }
    if (tid < 80) a1_s[tid] = a1p[tid];
    if (tid == 0) bf_s = bfp[0];
    if (tid < 200) {
        cate_s[tid] = catep[(size_t)b*200 + tid];
        mask_s[tid] = maskp[(size_t)b*200 + tid];   // coalesced once, read from LDS in phase 1
    }
    __syncthreads();

    // ---------- Phase 0b: folded first-layer operands (all-coalesced W1 reads) ----------
    // info@W1 = q@(W1a+W1c) + k@(W1b-W1c+diag(q)W1d);  Mt[h][d] = (W1b-W1c+q_d W1d)[d][h]
    #pragma unroll 4
    for (int j = tid; j < 5120; j += 256) {      // j = d*80 + h : 3 coalesced streams
        int d = j / 80, h = j - d*80;
        float m = W1p[5120 + j] - W1p[10240 + j] + q_s[d] * W1p[15360 + j];
        Mt[h*72 + d] = f2bf(m);                  // u16 scatter into LDS (cheap vs L2 scatter)
    }
    if (tid < 160) {                             // qW partials: 2 x 80 threads x 32 d's
        int p = tid / 80, h = tid - p*80;
        float acc0 = 0.f, acc1 = 0.f;
        int d0 = p * 32;
        #pragma unroll 4
        for (int d = d0; d < d0 + 32; d += 2) {  // dual accumulators, 16 loads in flight
            acc0 += q_s[d]   * (W1p[d*80 + h]     + W1p[(128+d)*80 + h]);
            acc1 += q_s[d+1] * (W1p[(d+1)*80 + h] + W1p[(129+d)*80 + h]);
        }
        qW2[tid] = acc0 + acc1;
    }
    #pragma unroll 4
    for (int e = tid; e < 3200; e += 256) {      // W2t[g][h] = bf16(W2[h][g])
        int n = e % 40, kk = e / 40;
        W2t[n*104 + kk] = f2bf(W2p[e]);
    }
    __syncthreads();
    if (tid < 80) qW_s[tid] = b1p[tid] + qW2[tid] + qW2[80 + tid];
    __syncthreads();

    // ---------- Phase 1: MLP via swapped-operand MFMA, one 16-row t-tile per wave ----------
    // GEMM1: H1^T[h][t] = mfma(Mt-frag as A, k-frag as B); lane holds
    // H1T(h = 16*nt + 4*q4 + r, t = t0 + i16) in acc[r]. PReLU'd values are
    // packed to bf16 pairs P[nt] and regrouped across the 4 q4-groups via shfl
    // to build GEMM2 B-fragments: B[k = 32*kc + 8*q4 + j][t = i16], where the
    // source of (kc, qt, j) is group qs = 2*(qt&1) + (j>>2), reg (nt = 2*kc +
    // (qt>>1), r = j&3). kc=2, qt>=2 is the zero K-pad (h = 80..95).
    {
        int mt = wid;
        float4 f0, f1, f2, f3;
        {
            int arow = mt*16 + i16; if (arow > 199) arow = 199;  // clamp tail (rows discarded)
            const float4* kr = (const float4*)(kb + arow*64);
            f0 = kr[2*q4];     f1 = kr[2*q4 + 1];
            f2 = kr[8 + 2*q4]; f3 = kr[9 + 2*q4];
        }
        const int srcA = i16 + ((lane & 16) << 1);   // lane of group qs = 2*(q4&1)
        const int srcB = srcA + 16;                  // lane of group qs+1
        const bool hi4 = (q4 >> 1) != 0;
        for (; mt < 13; mt += 4) {
            short8 ka0 = cvt8(f0, f1);
            short8 ka1 = cvt8(f2, f3);
            {   // prefetch next tile into the now-dead f regs (hides HBM latency)
                int nmt = mt + 4; if (nmt > 12) nmt = 12;        // harmless redundant tail load
                int narow = nmt*16 + i16; if (narow > 199) narow = 199;
                const float4* nkr = (const float4*)(kb + narow*64);
                f0 = nkr[2*q4];     f1 = nkr[2*q4 + 1];
                f2 = nkr[8 + 2*q4]; f3 = nkr[9 + 2*q4];
            }
            unsigned int P0[2], P1[2], P2[2], P3[2], P4[2];
#define G1(nt, Pd) { \
            const int n0 = (nt)*16; \
            float4 qw4 = *(const float4*)&qW_s[n0 + q4*4]; \
            f32x4 acc = { qw4.x, qw4.y, qw4.z, qw4.w }; \
            short8 m0 = *(const short8*)&Mt[(n0+i16)*72 + q4*8]; \
            short8 m1 = *(const short8*)&Mt[(n0+i16)*72 + 32 + q4*8]; \
            acc = __builtin_amdgcn_mfma_f32_16x16x32_bf16(m0, ka0, acc, 0, 0, 0); \
            acc = __builtin_amdgcn_mfma_f32_16x16x32_bf16(m1, ka1, acc, 0, 0, 0); \
            float4 al4 = *(const float4*)&a1_s[n0 + q4*4]; \
            float y0 = (acc[0] > 0.f) ? acc[0] : al4.x * acc[0]; \
            float y1 = (acc[1] > 0.f) ? acc[1] : al4.y * acc[1]; \
            float y2 = (acc[2] > 0.f) ? acc[2] : al4.z * acc[2]; \
            float y3 = (acc[3] > 0.f) ? acc[3] : al4.w * acc[3]; \
            Pd[0] = (unsigned int)f2bf(y0) | ((unsigned int)f2bf(y1) << 16); \
            Pd[1] = (unsigned int)f2bf(y2) | ((unsigned int)f2bf(y3) << 16); }
            G1(0, P0) G1(1, P1) G1(2, P2) G1(3, P3) G1(4, P4)
#undef G1
            // in-register regroup: build GEMM2 B-fragments (3 K-chunks of 32)
            union BW { unsigned int w[4]; short8 v; } B0, B1, B2;
            {
                int xa, xb, ya, yb, za, zb, wa, wb;
                xa = __shfl((int)P0[0], srcA); xb = __shfl((int)P0[1], srcA);
                ya = __shfl((int)P0[0], srcB); yb = __shfl((int)P0[1], srcB);
                za = __shfl((int)P1[0], srcA); zb = __shfl((int)P1[1], srcA);
                wa = __shfl((int)P1[0], srcB); wb = __shfl((int)P1[1], srcB);
                B0.w[0] = hi4 ? (unsigned)za : (unsigned)xa;
                B0.w[1] = hi4 ? (unsigned)zb : (unsigned)xb;
                B0.w[2] = hi4 ? (unsigned)wa : (unsigned)ya;
                B0.w[3] = hi4 ? (unsigned)wb : (unsigned)yb;
                xa = __shfl((int)P2[0], srcA); xb = __shfl((int)P2[1], srcA);
                ya = __shfl((int)P2[0], srcB); yb = __shfl((int)P2[1], srcB);
                za = __shfl((int)P3[0], srcA); zb = __shfl((int)P3[1], srcA);
                wa = __shfl((int)P3[0], srcB); wb = __shfl((int)P3[1], srcB);
                B1.w[0] = hi4 ? (unsigned)za : (unsigned)xa;
                B1.w[1] = hi4 ? (unsigned)zb : (unsigned)xb;
                B1.w[2] = hi4 ? (unsigned)wa : (unsigned)ya;
                B1.w[3] = hi4 ? (unsigned)wb : (unsigned)yb;
                xa = __shfl((int)P4[0], srcA); xb = __shfl((int)P4[1], srcA);
                ya = __shfl((int)P4[0], srcB); yb = __shfl((int)P4[1], srcB);
                B2.w[0] = hi4 ? 0u : (unsigned)xa;   // h=80..95: zero K-pad
                B2.w[1] = hi4 ? 0u : (unsigned)xb;
                B2.w[2] = hi4 ? 0u : (unsigned)ya;
                B2.w[3] = hi4 ? 0u : (unsigned)yb;
            }
            // GEMM2 swapped: H2^T[g][t] = mfma(W2t-frag as A, H1^T-frag as B)
            float part = 0.f;
            #pragma unroll
            for (int gt = 0; gt < 3; ++gt) {
                const int g0 = gt*16;
                float4 b24 = *(const float4*)&b2_s[g0 + q4*4];
                f32x4 acc = { b24.x, b24.y, b24.z, b24.w };
                short8 w0 = *(const short8*)&W2t[(g0+i16)*104 + q4*8];
                short8 w1 = *(const short8*)&W2t[(g0+i16)*104 + 32 + q4*8];
                short8 w2 = *(const short8*)&W2t[(g0+i16)*104 + 64 + q4*8];
                acc = __builtin_amdgcn_mfma_f32_16x16x32_bf16(w0, B0.v, acc, 0, 0, 0);
                acc = __builtin_amdgcn_mfma_f32_16x16x32_bf16(w1, B1.v, acc, 0, 0, 0);
                acc = __builtin_amdgcn_mfma_f32_16x16x32_bf16(w2, B2.v, acc, 0, 0, 0);
                float4 a24 = *(const float4*)&a2_s[g0 + q4*4];
                float4 wf4 = *(const float4*)&wf_s[g0 + q4*4];   // zero-padded g 40..47 contribute 0
                part += ((acc[0] > 0.f) ? acc[0] : a24.x * acc[0]) * wf4.x;
                part += ((acc[1] > 0.f) ? acc[1] : a24.y * acc[1]) * wf4.y;
                part += ((acc[2] > 0.f) ? acc[2] : a24.z * acc[2]) * wf4.z;
                part += ((acc[3] > 0.f) ? acc[3] : a24.w * acc[3]) * wf4.w;
            }
            part += __shfl_xor(part, 16, 64);    // reduce over the 4 q4-groups
            part += __shfl_xor(part, 32, 64);
            if (lane < 16) {
                int t = mt*16 + lane;
                if (t < 200) {
                    float v = (mask_s[t] == 0) ? NEG_MASK : (bf_s + part);
                    logits_s[t] = v * 0.125f;    // /sqrt(64)
                }
            }
        }
    }
    __syncthreads();

    // ---------- Phase 2: softmax + per-category weight sums ----------
    {
        float4 z = {0.f, 0.f, 0.f, 0.f};
        float4* ca4 = (float4*)cate_acc;                 // Mt/W2t dead now
        for (int i = tid; i < 1024; i += 256) ca4[i] = z;
    }
    // preload phase-3 batch 0 (contiguous 50-row chunk per wave); the softmax
    // barriers' vmcnt(0) drain hides the L3 latency behind the reduction work
    const int t0 = wid * 50;
    float kd[10];
    #pragma unroll
    for (int j = 0; j < 10; ++j) kd[j] = kb[(t0 + j)*64 + lane];

    float x = (tid < 200) ? logits_s[tid] : -3.0e38f;
    float m = x;
    #pragma unroll
    for (int off = 32; off >= 1; off >>= 1) m = fmaxf(m, __shfl_xor(m, off, 64));
    if (lane == 0) red_s[wid] = m;
    __syncthreads();
    float mx = fmaxf(fmaxf(red_s[0], red_s[1]), fmaxf(red_s[2], red_s[3]));
    float e = (tid < 200) ? __expf(x - mx) : 0.f;   // masked rows underflow to exact 0
    float s = e;
    #pragma unroll
    for (int off = 32; off >= 1; off >>= 1) s += __shfl_xor(s, off, 64);
    if (lane == 0) red_s[4 + wid] = s;
    __syncthreads();
    float tot = red_s[4] + red_s[5] + red_s[6] + red_s[7];
    float wv = e / tot;
    if (tid < 200) {
        logits_s[tid] = wv;   // reuse as w[t]
        if (wv > 0.f) atomicAdd(&s_c[cate_s[tid]], wv);
    }
    __syncthreads();

    // ---------- Phase 3: pooling, 10-deep pipelined load batches (lanes = d) ----------
    for (int i = 0; i < 50; i += 10) {
        float nkd[10];
        const bool more = (i + 10 < 50);
        if (more) {                                   // issue next batch's loads first
            #pragma unroll
            for (int j = 0; j < 10; ++j) nkd[j] = kb[(t0 + i + 10 + j)*64 + lane];
        }
        float w_[10]; int c_[10];
        #pragma unroll
        for (int j = 0; j < 10; ++j) { w_[j] = logits_s[t0+i+j]; c_[j] = cate_s[t0+i+j]; }
        #pragma unroll
        for (int j = 0; j < 10; ++j) {
            float w = w_[j];                          // wave-uniform -> uniform branch
            if (w > 0.f) atomicAdd(&cate_acc[c_[j]*64 + lane], w * kd[j]);
        }
        if (more) {
            #pragma unroll
            for (int j = 0; j < 10; ++j) kd[j] = nkd[j];
        }
    }
    __syncthreads();

    if (tid < 64) {   // user_interest = sum over categories of raw weighted sums
        float ui = 0.f;
        #pragma unroll 8
        for (int c = 0; c < 64; ++c) ui += cate_acc[c*64 + tid];
        outp[(size_t)b*64 + tid] = ui;
    }
    {
        float* outc = outp + (size_t)(4096*64) + (size_t)b*4096;
        #pragma unroll
        for (int ii = 0; ii < 4; ++ii) {              // float4 stores, 4 iters
            int i = tid*4 + ii*1024;
            float inv = 1.0f / (s_c[i >> 6] + 1e-10f);
            float4 v = *(const float4*)&cate_acc[i];
            v.x *= inv; v.y *= inv; v.z *= inv; v.w *= inv;
            *(float4*)&outc[i] = v;
        }
    }
}

extern "C" void kernel_launch(void* const* d_in, const int* in_sizes, int n_in,
                              void* d_out, int out_size, void* d_ws, size_t ws_size,
                              hipStream_t stream) {
    din_kernel<<<4096, 256, 0, stream>>>(
        (const float*)d_in[0],   // q
        (const float*)d_in[1],   // k
        (const int*)d_in[2],     // mask
        (const int*)d_in[3],     // hist_cate
        (const float*)d_in[5],   // W1 (d_in[4] = cate_count scalar)
        (const float*)d_in[6],   // b1
        (const float*)d_in[7],   // a1
        (const float*)d_in[8],   // W2
        (const float*)d_in[9],   // b2
        (const float*)d_in[10],  // a2
        (const float*)d_in[11],  // Wf
        (const float*)d_in[12],  // bf
        (float*)d_out);
}

// Round 5
// 487.101 us; speedup vs baseline: 1.4481x; 1.4481x over previous
//
#include <hip/hip_runtime.h>

typedef unsigned short u16;
typedef short short8 __attribute__((ext_vector_type(8)));   // 8 bf16 as i16 (MFMA operand)
typedef float f32x4 __attribute__((ext_vector_type(4)));

#define NEG_MASK -4294967295.0f   // -2^32+1 in f32

__device__ __forceinline__ u16 f2bf(float f) {
    unsigned int x = __float_as_uint(f);
    unsigned int r = (x + 0x7FFFu + ((x >> 16) & 1u)) >> 16;   // RNE
    return (u16)r;
}
__device__ __forceinline__ short8 cvt8(float4 a, float4 b) {
    union { short8 v; u16 u[8]; } r;
    r.u[0] = f2bf(a.x); r.u[1] = f2bf(a.y); r.u[2] = f2bf(a.z); r.u[3] = f2bf(a.w);
    r.u[4] = f2bf(b.x); r.u[5] = f2bf(b.y); r.u[6] = f2bf(b.z); r.u[7] = f2bf(b.w);
    return r.v;
}

// B=4096, T=200 (13 tiles of 16), D=64, H1=80, H2=40(pad 48, K2 pad 96), C=64
// Round 5: r3/r4 both died at container level (same source, never executed).
// Hedge: drop the min-waves launch-bounds arg -> plain __launch_bounds__(256)
// (the r0-proven compile path). Unconstrained allocator on the r2 structure's
// ~75-reg live set should land ~80-100 VGPR -> 5 waves/SIMD -> 5 blocks/CU,
// same occupancy target as the (256,5) experiment, zero spill risk.
// Same swapped-operand MFMA structure as r2 (H1 LDS buffer eliminated,
// LDS 26.1 KB); phase-3 w/c read inline from LDS.
__global__ __launch_bounds__(256) void din_kernel(
    const float* __restrict__ qp, const float* __restrict__ kp,
    const int* __restrict__ maskp, const int* __restrict__ catep,
    const float* __restrict__ W1p, const float* __restrict__ b1p,
    const float* __restrict__ a1p, const float* __restrict__ W2p,
    const float* __restrict__ b2p, const float* __restrict__ a2p,
    const float* __restrict__ wfp, const float* __restrict__ bfp,
    float* __restrict__ outp)
{
    // Mt (A-op GEMM1, [h][d], stride 72) | W2t (A-op GEMM2, [g][h], stride 104, zero-padded)
    // Reused after the GEMM phase as cate_acc[64][64] f32 (16384 B <= 21504 B)
    __shared__ __align__(16) u16 MtW2t[80*72 + 48*104];      // 21504 B
    __shared__ __align__(16) float logits_s[200];            // phase0: qW partials alias
    __shared__ __align__(16) float q_s[64], qW_s[80], a1_s[80];
    __shared__ __align__(16) float a2_s[48], b2_s[48], wf_s[48];
    __shared__ float s_c[64], red_s[8], bf_s;
    __shared__ int cate_s[200];
    __shared__ int mask_s[200];

    u16* Mt  = MtW2t;
    u16* W2t = MtW2t + 80*72;
    float* cate_acc = (float*)MtW2t;
    float* qW2 = logits_s;   // alias: dead before logits are first written (phase 1)

    const int tid  = threadIdx.x;
    const int b    = blockIdx.x;
    const int wid  = tid >> 6;
    const int lane = tid & 63;
    const int i16  = lane & 15;
    const int q4   = lane >> 4;
    const float* kb = kp + (size_t)b * 12800;   // k[b] : [200][64] f32

    // ---------- Phase 0a: zeros + scalar staging ----------
    {
        unsigned int* w2z = (unsigned int*)W2t;
        for (int i = tid; i < (48*104)/2; i += 256) w2z[i] = 0u;  // W2t pad rows/cols
    }
    if (tid < 64) { s_c[tid] = 0.f; q_s[tid] = qp[(size_t)b*64 + tid]; }
    if (tid < 48) {
        wf_s[tid] = (tid < 40) ? wfp[tid] : 0.f;
        a2_s[tid] = (tid < 40) ? a2p[tid] : 0.f;
        b2_s[tid] = (tid < 40) ? b2p[tid] : 0.f;
    }
    if (tid < 80) a1_s[tid] = a1p[tid];
    if (tid == 0) bf_s = bfp[0];
    if (tid < 200) {
        cate_s[tid] = catep[(size_t)b*200 + tid];
        mask_s[tid] = maskp[(size_t)b*200 + tid];   // coalesced once, read from LDS in phase 1
    }
    __syncthreads();

    // ---------- Phase 0b: folded first-layer operands (all-coalesced W1 reads) ----------
    // info@W1 = q@(W1a+W1c) + k@(W1b-W1c+diag(q)W1d);  Mt[h][d] = (W1b-W1c+q_d W1d)[d][h]
    #pragma unroll 4
    for (int j = tid; j < 5120; j += 256) {      // j = d*80 + h : 3 coalesced streams
        int d = j / 80, h = j - d*80;
        float m = W1p[5120 + j] - W1p[10240 + j] + q_s[d] * W1p[15360 + j];
        Mt[h*72 + d] = f2bf(m);                  // u16 scatter into LDS (cheap vs L2 scatter)
    }
    if (tid < 160) {                             // qW partials: 2 x 80 threads x 32 d's
        int p = tid / 80, h = tid - p*80;
        float acc0 = 0.f, acc1 = 0.f;
        int d0 = p * 32;
        #pragma unroll 4
        for (int d = d0; d < d0 + 32; d += 2) {  // dual accumulators, 16 loads in flight
            acc0 += q_s[d]   * (W1p[d*80 + h]     + W1p[(128+d)*80 + h]);
            acc1 += q_s[d+1] * (W1p[(d+1)*80 + h] + W1p[(129+d)*80 + h]);
        }
        qW2[tid] = acc0 + acc1;
    }
    #pragma unroll 4
    for (int e = tid; e < 3200; e += 256) {      // W2t[g][h] = bf16(W2[h][g])
        int n = e % 40, kk = e / 40;
        W2t[n*104 + kk] = f2bf(W2p[e]);
    }
    __syncthreads();
    if (tid < 80) qW_s[tid] = b1p[tid] + qW2[tid] + qW2[80 + tid];
    __syncthreads();

    // ---------- Phase 1: MLP via swapped-operand MFMA, one 16-row t-tile per wave ----------
    // GEMM1: H1^T[h][t] = mfma(Mt-frag as A, k-frag as B); lane holds
    // H1T(h = 16*nt + 4*q4 + r, t = t0 + i16) in acc[r]. PReLU'd values are
    // packed to bf16 pairs P[nt] and regrouped across the 4 q4-groups via shfl
    // to build GEMM2 B-fragments: B[k = 32*kc + 8*q4 + j][t = i16], where the
    // source of (kc, qt, j) is group qs = 2*(qt&1) + (j>>2), reg (nt = 2*kc +
    // (qt>>1), r = j&3). kc=2, qt>=2 is the zero K-pad (h = 80..95).
    {
        int mt = wid;
        float4 f0, f1, f2, f3;
        {
            int arow = mt*16 + i16; if (arow > 199) arow = 199;  // clamp tail (rows discarded)
            const float4* kr = (const float4*)(kb + arow*64);
            f0 = kr[2*q4];     f1 = kr[2*q4 + 1];
            f2 = kr[8 + 2*q4]; f3 = kr[9 + 2*q4];
        }
        const int srcA = i16 + ((lane & 16) << 1);   // lane of group qs = 2*(q4&1)
        const int srcB = srcA + 16;                  // lane of group qs+1
        const bool hi4 = (q4 >> 1) != 0;
        for (; mt < 13; mt += 4) {
            short8 ka0 = cvt8(f0, f1);
            short8 ka1 = cvt8(f2, f3);
            {   // prefetch next tile into the now-dead f regs (hides HBM latency)
                int nmt = mt + 4; if (nmt > 12) nmt = 12;        // harmless redundant tail load
                int narow = nmt*16 + i16; if (narow > 199) narow = 199;
                const float4* nkr = (const float4*)(kb + narow*64);
                f0 = nkr[2*q4];     f1 = nkr[2*q4 + 1];
                f2 = nkr[8 + 2*q4]; f3 = nkr[9 + 2*q4];
            }
            unsigned int P0[2], P1[2], P2[2], P3[2], P4[2];
#define G1(nt, Pd) { \
            const int n0 = (nt)*16; \
            float4 qw4 = *(const float4*)&qW_s[n0 + q4*4]; \
            f32x4 acc = { qw4.x, qw4.y, qw4.z, qw4.w }; \
            short8 m0 = *(const short8*)&Mt[(n0+i16)*72 + q4*8]; \
            short8 m1 = *(const short8*)&Mt[(n0+i16)*72 + 32 + q4*8]; \
            acc = __builtin_amdgcn_mfma_f32_16x16x32_bf16(m0, ka0, acc, 0, 0, 0); \
            acc = __builtin_amdgcn_mfma_f32_16x16x32_bf16(m1, ka1, acc, 0, 0, 0); \
            float4 al4 = *(const float4*)&a1_s[n0 + q4*4]; \
            float y0 = (acc[0] > 0.f) ? acc[0] : al4.x * acc[0]; \
            float y1 = (acc[1] > 0.f) ? acc[1] : al4.y * acc[1]; \
            float y2 = (acc[2] > 0.f) ? acc[2] : al4.z * acc[2]; \
            float y3 = (acc[3] > 0.f) ? acc[3] : al4.w * acc[3]; \
            Pd[0] = (unsigned int)f2bf(y0) | ((unsigned int)f2bf(y1) << 16); \
            Pd[1] = (unsigned int)f2bf(y2) | ((unsigned int)f2bf(y3) << 16); }
            G1(0, P0) G1(1, P1) G1(2, P2) G1(3, P3) G1(4, P4)
#undef G1
            // in-register regroup: build GEMM2 B-fragments (3 K-chunks of 32)
            union BW { unsigned int w[4]; short8 v; } B0, B1, B2;
            {
                int xa, xb, ya, yb, za, zb, wa, wb;
                xa = __shfl((int)P0[0], srcA); xb = __shfl((int)P0[1], srcA);
                ya = __shfl((int)P0[0], srcB); yb = __shfl((int)P0[1], srcB);
                za = __shfl((int)P1[0], srcA); zb = __shfl((int)P1[1], srcA);
                wa = __shfl((int)P1[0], srcB); wb = __shfl((int)P1[1], srcB);
                B0.w[0] = hi4 ? (unsigned)za : (unsigned)xa;
                B0.w[1] = hi4 ? (unsigned)zb : (unsigned)xb;
                B0.w[2] = hi4 ? (unsigned)wa : (unsigned)ya;
                B0.w[3] = hi4 ? (unsigned)wb : (unsigned)yb;
                xa = __shfl((int)P2[0], srcA); xb = __shfl((int)P2[1], srcA);
                ya = __shfl((int)P2[0], srcB); yb = __shfl((int)P2[1], srcB);
                za = __shfl((int)P3[0], srcA); zb = __shfl((int)P3[1], srcA);
                wa = __shfl((int)P3[0], srcB); wb = __shfl((int)P3[1], srcB);
                B1.w[0] = hi4 ? (unsigned)za : (unsigned)xa;
                B1.w[1] = hi4 ? (unsigned)zb : (unsigned)xb;
                B1.w[2] = hi4 ? (unsigned)wa : (unsigned)ya;
                B1.w[3] = hi4 ? (unsigned)wb : (unsigned)yb;
                xa = __shfl((int)P4[0], srcA); xb = __shfl((int)P4[1], srcA);
                ya = __shfl((int)P4[0], srcB); yb = __shfl((int)P4[1], srcB);
                B2.w[0] = hi4 ? 0u : (unsigned)xa;   // h=80..95: zero K-pad
                B2.w[1] = hi4 ? 0u : (unsigned)xb;
                B2.w[2] = hi4 ? 0u : (unsigned)ya;
                B2.w[3] = hi4 ? 0u : (unsigned)yb;
            }
            // GEMM2 swapped: H2^T[g][t] = mfma(W2t-frag as A, H1^T-frag as B)
            float part = 0.f;
            #pragma unroll
            for (int gt = 0; gt < 3; ++gt) {
                const int g0 = gt*16;
                float4 b24 = *(const float4*)&b2_s[g0 + q4*4];
                f32x4 acc = { b24.x, b24.y, b24.z, b24.w };
                short8 w0 = *(const short8*)&W2t[(g0+i16)*104 + q4*8];
                short8 w1 = *(const short8*)&W2t[(g0+i16)*104 + 32 + q4*8];
                short8 w2 = *(const short8*)&W2t[(g0+i16)*104 + 64 + q4*8];
                acc = __builtin_amdgcn_mfma_f32_16x16x32_bf16(w0, B0.v, acc, 0, 0, 0);
                acc = __builtin_amdgcn_mfma_f32_16x16x32_bf16(w1, B1.v, acc, 0, 0, 0);
                acc = __builtin_amdgcn_mfma_f32_16x16x32_bf16(w2, B2.v, acc, 0, 0, 0);
                float4 a24 = *(const float4*)&a2_s[g0 + q4*4];
                float4 wf4 = *(const float4*)&wf_s[g0 + q4*4];   // zero-padded g 40..47 contribute 0
                part += ((acc[0] > 0.f) ? acc[0] : a24.x * acc[0]) * wf4.x;
                part += ((acc[1] > 0.f) ? acc[1] : a24.y * acc[1]) * wf4.y;
                part += ((acc[2] > 0.f) ? acc[2] : a24.z * acc[2]) * wf4.z;
                part += ((acc[3] > 0.f) ? acc[3] : a24.w * acc[3]) * wf4.w;
            }
            part += __shfl_xor(part, 16, 64);    // reduce over the 4 q4-groups
            part += __shfl_xor(part, 32, 64);
            if (lane < 16) {
                int t = mt*16 + lane;
                if (t < 200) {
                    float v = (mask_s[t] == 0) ? NEG_MASK : (bf_s + part);
                    logits_s[t] = v * 0.125f;    // /sqrt(64)
                }
            }
        }
    }
    __syncthreads();

    // ---------- Phase 2: softmax + per-category weight sums ----------
    {
        float4 z = {0.f, 0.f, 0.f, 0.f};
        float4* ca4 = (float4*)cate_acc;                 // Mt/W2t dead now
        for (int i = tid; i < 1024; i += 256) ca4[i] = z;
    }
    // preload phase-3 batch 0 (contiguous 50-row chunk per wave); the softmax
    // barriers' vmcnt(0) drain hides the L3 latency behind the reduction work
    const int t0 = wid * 50;
    float kd[10];
    #pragma unroll
    for (int j = 0; j < 10; ++j) kd[j] = kb[(t0 + j)*64 + lane];

    float x = (tid < 200) ? logits_s[tid] : -3.0e38f;
    float m = x;
    #pragma unroll
    for (int off = 32; off >= 1; off >>= 1) m = fmaxf(m, __shfl_xor(m, off, 64));
    if (lane == 0) red_s[wid] = m;
    __syncthreads();
    float mx = fmaxf(fmaxf(red_s[0], red_s[1]), fmaxf(red_s[2], red_s[3]));
    float e = (tid < 200) ? __expf(x - mx) : 0.f;   // masked rows underflow to exact 0
    float s = e;
    #pragma unroll
    for (int off = 32; off >= 1; off >>= 1) s += __shfl_xor(s, off, 64);
    if (lane == 0) red_s[4 + wid] = s;
    __syncthreads();
    float tot = red_s[4] + red_s[5] + red_s[6] + red_s[7];
    float wv = e / tot;
    if (tid < 200) {
        logits_s[tid] = wv;   // reuse as w[t]
        if (wv > 0.f) atomicAdd(&s_c[cate_s[tid]], wv);
    }
    __syncthreads();

    // ---------- Phase 3: pooling, 10-deep pipelined load batches (lanes = d) ----------
    // w/c read inline from LDS (wave-uniform broadcast) to keep the live set
    // small: only kd/nkd (20 regs) carry across the pipeline.
    for (int i = 0; i < 50; i += 10) {
        float nkd[10];
        const bool more = (i + 10 < 50);
        if (more) {                                   // issue next batch's loads first
            #pragma unroll
            for (int j = 0; j < 10; ++j) nkd[j] = kb[(t0 + i + 10 + j)*64 + lane];
        }
        #pragma unroll
        for (int j = 0; j < 10; ++j) {
            float w = logits_s[t0 + i + j];           // wave-uniform -> uniform branch
            if (w > 0.f) atomicAdd(&cate_acc[cate_s[t0 + i + j]*64 + lane], w * kd[j]);
        }
        if (more) {
            #pragma unroll
            for (int j = 0; j < 10; ++j) kd[j] = nkd[j];
        }
    }
    __syncthreads();

    if (tid < 64) {   // user_interest = sum over categories of raw weighted sums
        float ui = 0.f;
        #pragma unroll 8
        for (int c = 0; c < 64; ++c) ui += cate_acc[c*64 + tid];
        outp[(size_t)b*64 + tid] = ui;
    }
    {
        float* outc = outp + (size_t)(4096*64) + (size_t)b*4096;
        #pragma unroll
        for (int ii = 0; ii < 4; ++ii) {              // float4 stores, 4 iters
            int i = tid*4 + ii*1024;
            float inv = 1.0f / (s_c[i >> 6] + 1e-10f);
            float4 v = *(const float4*)&cate_acc[i];
            v.x *= inv; v.y *= inv; v.z *= inv; v.w *= inv;
            *(float4*)&outc[i] = v;
        }
    }
}

extern "C" void kernel_launch(void* const* d_in, const int* in_sizes, int n_in,
                              void* d_out, int out_size, void* d_ws, size_t ws_size,
                              hipStream_t stream) {
    din_kernel<<<4096, 256, 0, stream>>>(
        (const float*)d_in[0],   // q
        (const float*)d_in[1],   // k
        (const int*)d_in[2],     // mask
        (const int*)d_in[3],     // hist_cate
        (const float*)d_in[5],   // W1 (d_in[4] = cate_count scalar)
        (const float*)d_in[6],   // b1
        (const float*)d_in[7],   // a1
        (const float*)d_in[8],   // W2
        (const float*)d_in[9],   // b2
        (const float*)d_in[10],  // a2
        (const float*)d_in[11],  // Wf
        (const float*)d_in[12],  // bf
        (float*)d_out);
}